// Round 7
// baseline (1049.655 us; speedup 1.0000x reference)
//
#include <hip/hip_runtime.h>

// glibc math.h (pulled in transitively) declares its own __exp2f -> collides
// with HIP's intrinsic name on this toolchain. Use the clang builtin directly.
#if __has_builtin(__builtin_amdgcn_exp2f)
#define EXP2F(x) __builtin_amdgcn_exp2f(x)
#else
#define EXP2F(x) exp2f(x)
#endif

// Problem constants (match reference)
constexpr int B  = 2;
constexpr int S  = 2048;
constexpr int D  = 1024;
constexpr int H  = 16;
constexpr int HD = 64;          // head dim
constexpr int BS = B * S;       // 4096 rows

// ---------------------------------------------------------------------------
// Tiled fp32 GEMM: C[M,N] = A[M,K] @ W[K,N] + bias
// TM=128, TN=64 or 128, KT=16, 256 threads. Per-thread acc = 8 x (TN/16).
// LDS double-buffered: ONE barrier per K-tile. Next tile's global loads issue
// before the FMA phase (latency hidden under ~2048 cyc of compute); the LDS
// stores for it go to buf^1 after compute (no conflict with concurrent
// readers of buf; the top-of-loop barrier orders store -> next-iter read).
// OUT_MODE 0: QKV projection — blockIdx.z selects (Wq,bq)/(Wk,bk)/(Wv,bv),
//             output written head-major: out + z*BS*D laid out [B,H,S,HD].
// OUT_MODE 1: plain row-major [BS, D] output (output projection).
// ---------------------------------------------------------------------------
template <int OUT_MODE, int TN>
__global__ __launch_bounds__(256) void gemm_kernel(
    const float* __restrict__ A,
    const float* __restrict__ W0, const float* __restrict__ b0,
    const float* __restrict__ W1, const float* __restrict__ b1,
    const float* __restrict__ W2, const float* __restrict__ b2,
    float* __restrict__ out)
{
    constexpr int TM = 128;
    constexpr int KT = 16;
    constexpr int NH = TN / 64;     // 1 or 2 column-halves

    const int z = (OUT_MODE == 0) ? blockIdx.z : 0;
    const float* __restrict__ W    = (z == 0) ? W0 : (z == 1) ? W1 : W2;
    const float* __restrict__ bias = (z == 0) ? b0 : (z == 1) ? b1 : b2;

    __shared__ float As[2][KT][TM];    // [buf][k][m] (transposed on store)
    __shared__ float Bs[2][KT][TN];    // [buf][k][n]

    const int tid = threadIdx.x;
    const int tx  = tid & 15;       // n-group
    const int ty  = tid >> 4;       // m-group
    const int m0  = blockIdx.x * TM;
    const int n0  = blockIdx.y * TN;

    // A-tile map: 128 rows x 16 k; 2 float4 along k per thread.
    const int a_row = tid >> 1;            // 0..127
    const int a_k   = (tid & 1) * 8;       // 0 or 8
    // W-tile map:
    //  TN=64 : 16 k-rows, 1 float4/thread
    //  TN=128: 2x8 k-rows, 2 float4/thread
    const int b_row = (TN == 64) ? (tid >> 4) : (tid >> 5);
    const int b_col = (TN == 64) ? ((tid & 15) * 4) : ((tid & 31) * 4);

    float acc[8][4 * NH] = {};

    float4 pa0, pa1, pb0, pb1;
    auto load_tile = [&](int k0) {
        pa0 = *reinterpret_cast<const float4*>(&A[(size_t)(m0 + a_row) * D + k0 + a_k]);
        pa1 = *reinterpret_cast<const float4*>(&A[(size_t)(m0 + a_row) * D + k0 + a_k + 4]);
        pb0 = *reinterpret_cast<const float4*>(&W[(size_t)(k0 + b_row) * D + n0 + b_col]);
        if constexpr (NH == 2)
            pb1 = *reinterpret_cast<const float4*>(&W[(size_t)(k0 + b_row + 8) * D + n0 + b_col]);
    };
    auto store_tile = [&](int buf) {
        As[buf][a_k + 0][a_row] = pa0.x;
        As[buf][a_k + 1][a_row] = pa0.y;
        As[buf][a_k + 2][a_row] = pa0.z;
        As[buf][a_k + 3][a_row] = pa0.w;
        As[buf][a_k + 4][a_row] = pa1.x;
        As[buf][a_k + 5][a_row] = pa1.y;
        As[buf][a_k + 6][a_row] = pa1.z;
        As[buf][a_k + 7][a_row] = pa1.w;
        *reinterpret_cast<float4*>(&Bs[buf][b_row][b_col]) = pb0;
        if constexpr (NH == 2)
            *reinterpret_cast<float4*>(&Bs[buf][b_row + 8][b_col]) = pb1;
    };

    load_tile(0);
    store_tile(0);
    int cur = 0;

    for (int k0 = 0; k0 < D; k0 += KT) {
        __syncthreads();                     // buf[cur] visible to all waves
        const bool more = (k0 + KT < D);
        if (more) load_tile(k0 + KT);        // flies under the FMA phase

        const float (*__restrict__ Asc)[TM] = As[cur];
        const float (*__restrict__ Bsc)[TN] = Bs[cur];
#pragma unroll
        for (int k = 0; k < KT; ++k) {
            float4 a0 = *reinterpret_cast<const float4*>(&Asc[k][ty * 4]);
            float4 a1 = *reinterpret_cast<const float4*>(&Asc[k][64 + ty * 4]);
            float4 c0 = *reinterpret_cast<const float4*>(&Bsc[k][tx * 4]);
            float a[8] = {a0.x, a0.y, a0.z, a0.w, a1.x, a1.y, a1.z, a1.w};
            float bb[4 * NH];
            bb[0] = c0.x; bb[1] = c0.y; bb[2] = c0.z; bb[3] = c0.w;
            if constexpr (NH == 2) {
                float4 c1 = *reinterpret_cast<const float4*>(&Bsc[k][64 + tx * 4]);
                bb[4] = c1.x; bb[5] = c1.y; bb[6] = c1.z; bb[7] = c1.w;
            }
#pragma unroll
            for (int i = 0; i < 8; ++i)
#pragma unroll
                for (int j = 0; j < 4 * NH; ++j)
                    acc[i][j] += a[i] * bb[j];
        }

        if (more) store_tile(cur ^ 1);       // other buffer: safe vs readers of cur
        cur ^= 1;
    }

#pragma unroll
    for (int mh = 0; mh < 2; ++mh) {
#pragma unroll
        for (int i = 0; i < 4; ++i) {
            const int m = m0 + mh * 64 + ty * 4 + i;
#pragma unroll
            for (int nh = 0; nh < NH; ++nh) {
                const int n = n0 + nh * 64 + tx * 4;
                float4 r;
                r.x = acc[mh * 4 + i][nh * 4 + 0] + bias[n + 0];
                r.y = acc[mh * 4 + i][nh * 4 + 1] + bias[n + 1];
                r.z = acc[mh * 4 + i][nh * 4 + 2] + bias[n + 2];
                r.w = acc[mh * 4 + i][nh * 4 + 3] + bias[n + 3];
                if constexpr (OUT_MODE == 1) {
                    *reinterpret_cast<float4*>(&out[(size_t)m * D + n]) = r;
                } else {
                    // head-major: out[z][b][h][s][d]; 64-col halves stay in one head
                    float* __restrict__ o = out + (size_t)z * BS * D;
                    const int bb2 = m >> 11;         // m / S
                    const int s   = m & (S - 1);
                    const int h   = n >> 6;
                    const int d   = n & (HD - 1);
                    *reinterpret_cast<float4*>(
                        &o[(((size_t)bb2 * H + h) * S + s) * HD + d]) = r;
                }
            }
        }
    }
}

// ---------------------------------------------------------------------------
// Flash-style attention per (b,h): Q,K,V in [B,H,S,HD] fp32.
// 256 threads, 64 query rows, KV tiles of 64.
// All LDS rows stride 68 floats (272B): every float4 access 16B-aligned;
// compute-phase reads are broadcast or <=2-way (free). 69.6 KB static LDS —
// gfx950 allows >64KB/workgroup (cf. verified 128KB 8-phase example).
// Q,K transposed [d][row] for QK^T float4 reads; P row-major [qrow][kv].
// Softmax in registers via 16-lane __shfl_xor groups; exp2-domain.
// K/V for tile t+1 prefetched into registers during tile t's compute.
// ---------------------------------------------------------------------------
__global__ __launch_bounds__(256) void attn_kernel(
    const float* __restrict__ qkv, float* __restrict__ ctx)
{
    constexpr int LP = 68;   // padded LDS row stride (floats)

    const int h  = blockIdx.y;
    const int b  = blockIdx.z;
    const int q0 = blockIdx.x * 64;

    const size_t head_off = (((size_t)b * H + h) * S) * HD;
    const float* __restrict__ Q = qkv + head_off;
    const float* __restrict__ K = qkv + (size_t)BS * D + head_off;
    const float* __restrict__ V = qkv + 2 * (size_t)BS * D + head_off;

    __shared__ float QsT[HD][LP];    // [d][q-row], scaled by 0.125*log2e
    __shared__ float KsT[HD][LP];    // [d][kv-row]
    __shared__ float Vs[64][LP];     // [kv-row][d]
    __shared__ float Ps[64][LP];     // [q-row][kv]

    const int tid = threadIdx.x;
    const int tx  = tid & 15;
    const int ty  = tid >> 4;

    // staging geometry: element offset = (c*256+tid)*4
    const int st_r   = tid >> 4;           // + c*16
    const int st_col = (tid & 15) * 4;

    float acc[4][4] = {};
    float m_reg[4], l_reg[4];
#pragma unroll
    for (int i = 0; i < 4; ++i) { m_reg[i] = -__builtin_inff(); l_reg[i] = 0.f; }

    // Stage Q transposed, folding in 0.125 * log2(e)
    constexpr float SCL = 0.125f * 1.44269504088896f;
#pragma unroll
    for (int c = 0; c < 4; ++c) {
        const int r = st_r + c * 16;
        float4 v = *reinterpret_cast<const float4*>(&Q[(size_t)(q0 + r) * HD + st_col]);
        QsT[st_col + 0][r] = v.x * SCL;
        QsT[st_col + 1][r] = v.y * SCL;
        QsT[st_col + 2][r] = v.z * SCL;
        QsT[st_col + 3][r] = v.w * SCL;
    }

    float4 pk[4], pv[4];
    auto load_kv = [&](int kv0) {
#pragma unroll
        for (int c = 0; c < 4; ++c) {
            const int r = st_r + c * 16;
            pk[c] = *reinterpret_cast<const float4*>(&K[(size_t)(kv0 + r) * HD + st_col]);
            pv[c] = *reinterpret_cast<const float4*>(&V[(size_t)(kv0 + r) * HD + st_col]);
        }
    };

    load_kv(0);

    for (int kv0 = 0; kv0 < S; kv0 += 64) {
        __syncthreads();   // prev PV done with Vs/Ps; QsT stores done (1st iter)
#pragma unroll
        for (int c = 0; c < 4; ++c) {
            const int r = st_r + c * 16;
            KsT[st_col + 0][r] = pk[c].x;
            KsT[st_col + 1][r] = pk[c].y;
            KsT[st_col + 2][r] = pk[c].z;
            KsT[st_col + 3][r] = pk[c].w;
            *reinterpret_cast<float4*>(&Vs[r][st_col]) = pv[c];
        }
        __syncthreads();

        if (kv0 + 64 < S) load_kv(kv0 + 64);   // overlaps QK^T + softmax + PV

        // S = Q K^T (in log2-domain): 4x4 per thread, float4 LDS reads
        float s[4][4] = {};
#pragma unroll 2
        for (int d = 0; d < HD; ++d) {
            float4 a4 = *reinterpret_cast<const float4*>(&QsT[d][ty * 4]);
            float4 b4 = *reinterpret_cast<const float4*>(&KsT[d][tx * 4]);
            float a[4]  = {a4.x, a4.y, a4.z, a4.w};
            float bb[4] = {b4.x, b4.y, b4.z, b4.w};
#pragma unroll
            for (int i = 0; i < 4; ++i)
#pragma unroll
                for (int j = 0; j < 4; ++j)
                    s[i][j] += a[i] * bb[j];
        }

        // Online softmax in registers: row 4ty+i lives in one 16-lane group
#pragma unroll
        for (int i = 0; i < 4; ++i) {
            float mx = fmaxf(fmaxf(s[i][0], s[i][1]), fmaxf(s[i][2], s[i][3]));
            mx = fmaxf(mx, __shfl_xor(mx, 1));
            mx = fmaxf(mx, __shfl_xor(mx, 2));
            mx = fmaxf(mx, __shfl_xor(mx, 4));
            mx = fmaxf(mx, __shfl_xor(mx, 8));
            const float m_new = fmaxf(m_reg[i], mx);
            const float alpha = EXP2F(m_reg[i] - m_new);
            float rs = 0.f;
#pragma unroll
            for (int j = 0; j < 4; ++j) {
                s[i][j] = EXP2F(s[i][j] - m_new);
                rs += s[i][j];
            }
            rs += __shfl_xor(rs, 1);
            rs += __shfl_xor(rs, 2);
            rs += __shfl_xor(rs, 4);
            rs += __shfl_xor(rs, 8);
            l_reg[i] = l_reg[i] * alpha + rs;
            m_reg[i] = m_new;
#pragma unroll
            for (int j = 0; j < 4; ++j)
                acc[i][j] *= alpha;
        }

        // Stage P row-major (float4 writes; stride 68 -> 2-way = free)
#pragma unroll
        for (int i = 0; i < 4; ++i) {
            float4 w4 = make_float4(s[i][0], s[i][1], s[i][2], s[i][3]);
            *reinterpret_cast<float4*>(&Ps[ty * 4 + i][tx * 4]) = w4;
        }
        __syncthreads();

        // ctx += P @ V : float4 reads on both operands
#pragma unroll 2
        for (int kq = 0; kq < 16; ++kq) {
            float4 p4[4];
#pragma unroll
            for (int i = 0; i < 4; ++i)
                p4[i] = *reinterpret_cast<const float4*>(&Ps[ty * 4 + i][kq * 4]);
            float pr[4][4] = {
                {p4[0].x, p4[0].y, p4[0].z, p4[0].w},
                {p4[1].x, p4[1].y, p4[1].z, p4[1].w},
                {p4[2].x, p4[2].y, p4[2].z, p4[2].w},
                {p4[3].x, p4[3].y, p4[3].z, p4[3].w}};
#pragma unroll
            for (int e = 0; e < 4; ++e) {
                float4 v4 = *reinterpret_cast<const float4*>(&Vs[kq * 4 + e][tx * 4]);
                float vv[4] = {v4.x, v4.y, v4.z, v4.w};
#pragma unroll
                for (int i = 0; i < 4; ++i)
#pragma unroll
                    for (int j = 0; j < 4; ++j)
                        acc[i][j] += pr[i][e] * vv[j];
            }
        }
    }

    // Normalize and write ctx in [B,S,D] (merge heads): col = h*64 + d
#pragma unroll
    for (int i = 0; i < 4; ++i) {
        const int q     = q0 + ty * 4 + i;
        const float inv = 1.f / l_reg[i];
        float4 r;
        r.x = acc[i][0] * inv;
        r.y = acc[i][1] * inv;
        r.z = acc[i][2] * inv;
        r.w = acc[i][3] * inv;
        *reinterpret_cast<float4*>(
            &ctx[((size_t)b * S + q) * D + h * HD + tx * 4]) = r;
    }
}

// ---------------------------------------------------------------------------
extern "C" void kernel_launch(void* const* d_in, const int* in_sizes, int n_in,
                              void* d_out, int out_size, void* d_ws, size_t ws_size,
                              hipStream_t stream)
{
    const float* hs = (const float*)d_in[0];
    const float* Wq = (const float*)d_in[1];
    const float* bq = (const float*)d_in[2];
    const float* Wk = (const float*)d_in[3];
    const float* bk = (const float*)d_in[4];
    const float* Wv = (const float*)d_in[5];
    const float* bv = (const float*)d_in[6];
    const float* Wo = (const float*)d_in[7];
    const float* bo = (const float*)d_in[8];

    float* qkv = (float*)d_ws;                       // 3 * BS * D floats, [3][B,H,S,HD]
    float* ctx = qkv + 3 * (size_t)BS * D;           // BS * D floats, [B,S,D]
    float* out = (float*)d_out;

    dim3 blk(256);

    // QKV projections (head-major output), 128x128 tiles -> 768 blocks
    gemm_kernel<0, 128><<<dim3(BS / 128, D / 128, 3), blk, 0, stream>>>(
        hs, Wq, bq, Wk, bk, Wv, bv, qkv);

    // Attention: 1024 blocks
    attn_kernel<<<dim3(S / 64, H, B), blk, 0, stream>>>(qkv, ctx);

    // Output projection, 128x64 tiles -> 512 blocks (2/CU for latency hiding)
    gemm_kernel<1, 64><<<dim3(BS / 128, D / 64, 1), blk, 0, stream>>>(
        ctx, Wo, bo, Wo, bo, Wo, bo, out);
}

// Round 8
// 793.360 us; speedup vs baseline: 1.3231x; 1.3231x over previous
//
#include <hip/hip_runtime.h>

// glibc math.h (transitively included) declares __exp2f -> name collision.
#if __has_builtin(__builtin_amdgcn_exp2f)
#define EXP2F(x) __builtin_amdgcn_exp2f(x)
#else
#define EXP2F(x) exp2f(x)
#endif

typedef short bf16x8 __attribute__((ext_vector_type(8)));   // 8 bf16 = 4 VGPRs
typedef float f32x4  __attribute__((ext_vector_type(4)));

// Problem constants (match reference)
constexpr int B  = 2;
constexpr int S  = 2048;
constexpr int D  = 1024;
constexpr int H  = 16;
constexpr int HD = 64;
constexpr int BS = B * S;       // 4096 rows

// ---------------- bf16 split helpers (error ~2^-18 relative) ----------------
__device__ __forceinline__ unsigned short bf16_rne(float f) {
    unsigned int u = __builtin_bit_cast(unsigned int, f);
    u += 0x7FFFu + ((u >> 16) & 1u);
    return (unsigned short)(u >> 16);
}
__device__ __forceinline__ float bf16_f32(unsigned short h) {
    unsigned int u = (unsigned int)h << 16;
    return __builtin_bit_cast(float, u);
}
__device__ __forceinline__ void split2(float f, unsigned short& h, unsigned short& l) {
    h = bf16_rne(f);
    l = bf16_rne(f - bf16_f32(h));
}

// ---------------------------------------------------------------------------
// Prepass 1: transpose + split the 4 weight matrices.
// W[k][n] fp32 -> WT_h/WT_l [z][n][k] bf16  (z: 0=Wq 1=Wk 2=Wv 3=Wo)
// ---------------------------------------------------------------------------
__global__ __launch_bounds__(256) void wsplit_kernel(
    const float* __restrict__ W0, const float* __restrict__ W1,
    const float* __restrict__ W2, const float* __restrict__ W3,
    unsigned short* __restrict__ wt_h, unsigned short* __restrict__ wt_l)
{
    const int z = blockIdx.z;
    const float* __restrict__ W = (z == 0) ? W0 : (z == 1) ? W1 : (z == 2) ? W2 : W3;
    __shared__ float T[64][68];
    const int k0 = blockIdx.x * 64, n0 = blockIdx.y * 64;
    const int t = threadIdx.x;
    const int r = t >> 4, c4 = (t & 15) * 4;
#pragma unroll
    for (int cc = 0; cc < 4; ++cc) {
        const int k = r + cc * 16;
        float4 v = *(const float4*)&W[(size_t)(k0 + k) * D + n0 + c4];
        T[k][c4 + 0] = v.x; T[k][c4 + 1] = v.y; T[k][c4 + 2] = v.z; T[k][c4 + 3] = v.w;
    }
    __syncthreads();
    const size_t base = (size_t)z * D * D;
#pragma unroll
    for (int cc = 0; cc < 4; ++cc) {
        const int n = r + cc * 16;
        ushort4 h4, l4;
        split2(T[c4 + 0][n], h4.x, l4.x);
        split2(T[c4 + 1][n], h4.y, l4.y);
        split2(T[c4 + 2][n], h4.z, l4.z);
        split2(T[c4 + 3][n], h4.w, l4.w);
        const size_t o = base + (size_t)(n0 + n) * D + k0 + c4;
        *(ushort4*)&wt_h[o] = h4;
        *(ushort4*)&wt_l[o] = l4;
    }
}

// ---------------------------------------------------------------------------
// Prepass 2: elementwise split fp32 -> bf16 hi/lo (for hidden_states).
// ---------------------------------------------------------------------------
__global__ __launch_bounds__(256) void asplit_kernel(
    const float* __restrict__ x, unsigned short* __restrict__ xh,
    unsigned short* __restrict__ xl, int n4)
{
    for (int i = blockIdx.x * 256 + threadIdx.x; i < n4; i += gridDim.x * 256) {
        float4 v = ((const float4*)x)[i];
        ushort4 h4, l4;
        split2(v.x, h4.x, l4.x);
        split2(v.y, h4.y, l4.y);
        split2(v.z, h4.z, l4.z);
        split2(v.w, h4.w, l4.w);
        ((ushort4*)xh)[i] = h4;
        ((ushort4*)xl)[i] = l4;
    }
}

// ---------------------------------------------------------------------------
// Split-bf16 MFMA GEMM: C = A @ W + bias, A [4096][1024], W via WT [N][K].
// C ~= Ah*Wh + Ah*Wl + Al*Wh (3 MFMAs / frag, fp32-level accuracy).
// BM=BN=128, BK=32, 256 thr = 4 waves (2x2), per-wave 64x64 = 4x4 frags of
// mfma_f32_16x16x32_bf16. LDS rows padded to 40 bf16 (80B): bank-perm
// {0,20,8,28,16,4,24,12} -> 2-way (free), all b128 16B-aligned.
// Frag layouts (m89-verified): A lane: row=l&15, k=8*(l>>4)+j (contig);
// B lane: col=l&15, k=8*(l>>4)+j; D lane: col=l&15, row=4*(l>>4)+r.
// OUT_MODE 0: z=blockIdx.z in {Q,K,V}, head-major out [z][b][h][s][d].
// OUT_MODE 1: z=3 (Wo), row-major [BS][D] out.
// ---------------------------------------------------------------------------
template <int OUT_MODE>
__global__ __launch_bounds__(256, 2) void mfma_gemm(
    const unsigned short* __restrict__ Ah, const unsigned short* __restrict__ Al,
    const unsigned short* __restrict__ Wh, const unsigned short* __restrict__ Wl,
    const float* __restrict__ b0, const float* __restrict__ b1,
    const float* __restrict__ b2, float* __restrict__ out)
{
    constexpr int BM = 128, BK = 32, LP = 40;
    const int z = (OUT_MODE == 0) ? blockIdx.z : 3;
    const float* __restrict__ bias = (OUT_MODE == 1) ? b0 : (z == 0 ? b0 : z == 1 ? b1 : b2);
    const unsigned short* __restrict__ WTh = Wh + (size_t)z * D * D;
    const unsigned short* __restrict__ WTl = Wl + (size_t)z * D * D;

    __shared__ __align__(16) unsigned short sm[2][4][BM][LP];  // [buf][Ah,Al,Wh,Wl]

    const int tid  = threadIdx.x;
    const int lane = tid & 63, wid = tid >> 6;
    const int wm = wid >> 1, wn = wid & 1;
    const int lrow = lane & 15, lk8 = (lane >> 4) * 8;
    const int m0 = blockIdx.x * BM, n0 = blockIdx.y * BM;

    // staging: row = tid>>1 (0..127), two 16B chunks at k = (tid&1)*16 + {0,8}
    const int srow = tid >> 1;
    const int sk   = (tid & 1) * 16;

    bf16x8 rah0, rah1, ral0, ral1, rwh0, rwh1, rwl0, rwl1;
    auto load_tile = [&](int k0) {
        const size_t ao = (size_t)(m0 + srow) * D + k0 + sk;
        rah0 = *(const bf16x8*)&Ah[ao];  rah1 = *(const bf16x8*)&Ah[ao + 8];
        ral0 = *(const bf16x8*)&Al[ao];  ral1 = *(const bf16x8*)&Al[ao + 8];
        const size_t wo = (size_t)(n0 + srow) * D + k0 + sk;
        rwh0 = *(const bf16x8*)&WTh[wo]; rwh1 = *(const bf16x8*)&WTh[wo + 8];
        rwl0 = *(const bf16x8*)&WTl[wo]; rwl1 = *(const bf16x8*)&WTl[wo + 8];
    };
    auto store_tile = [&](int buf) {
        *(bf16x8*)&sm[buf][0][srow][sk]     = rah0;
        *(bf16x8*)&sm[buf][0][srow][sk + 8] = rah1;
        *(bf16x8*)&sm[buf][1][srow][sk]     = ral0;
        *(bf16x8*)&sm[buf][1][srow][sk + 8] = ral1;
        *(bf16x8*)&sm[buf][2][srow][sk]     = rwh0;
        *(bf16x8*)&sm[buf][2][srow][sk + 8] = rwh1;
        *(bf16x8*)&sm[buf][3][srow][sk]     = rwl0;
        *(bf16x8*)&sm[buf][3][srow][sk + 8] = rwl1;
    };

    f32x4 acc[4][4] = {};

    load_tile(0);
    store_tile(0);
    int cur = 0;

    for (int ks = 0; ks < D / BK; ++ks) {
        __syncthreads();
        const bool more = (ks + 1 < D / BK);
        if (more) load_tile((ks + 1) * BK);

        bf16x8 ah[4], al[4], bh[4], bl[4];
#pragma unroll
        for (int m = 0; m < 4; ++m) {
            const int r = wm * 64 + m * 16 + lrow;
            ah[m] = *(const bf16x8*)&sm[cur][0][r][lk8];
            al[m] = *(const bf16x8*)&sm[cur][1][r][lk8];
        }
#pragma unroll
        for (int n = 0; n < 4; ++n) {
            const int r = wn * 64 + n * 16 + lrow;
            bh[n] = *(const bf16x8*)&sm[cur][2][r][lk8];
            bl[n] = *(const bf16x8*)&sm[cur][3][r][lk8];
        }
#pragma unroll
        for (int m = 0; m < 4; ++m)
#pragma unroll
            for (int n = 0; n < 4; ++n) {
                acc[m][n] = __builtin_amdgcn_mfma_f32_16x16x32_bf16(ah[m], bh[n], acc[m][n], 0, 0, 0);
                acc[m][n] = __builtin_amdgcn_mfma_f32_16x16x32_bf16(ah[m], bl[n], acc[m][n], 0, 0, 0);
                acc[m][n] = __builtin_amdgcn_mfma_f32_16x16x32_bf16(al[m], bh[n], acc[m][n], 0, 0, 0);
            }

        if (more) store_tile(cur ^ 1);
        cur ^= 1;
    }

#pragma unroll
    for (int m = 0; m < 4; ++m) {
        const int gm = m0 + wm * 64 + m * 16 + (lane >> 4) * 4;
#pragma unroll
        for (int n = 0; n < 4; ++n) {
            const int gn = n0 + wn * 64 + n * 16 + lrow;
            const float bv = bias[gn];
#pragma unroll
            for (int r = 0; r < 4; ++r) {
                const float v = acc[m][n][r] + bv;
                const int row = gm + r;
                if constexpr (OUT_MODE == 1) {
                    out[(size_t)row * D + gn] = v;
                } else {
                    float* __restrict__ o = out + (size_t)z * BS * D;
                    const int bb = row >> 11, s = row & (S - 1);
                    const int hh = gn >> 6, d = gn & (HD - 1);
                    o[(((size_t)bb * H + hh) * S + s) * HD + d] = v;
                }
            }
        }
    }
}

// ---------------------------------------------------------------------------
// Flash attention (unchanged fp32 core from round 7; 678us, LDS-BW-bound).
// SPLIT_OUT=1: epilogue writes ctx as split bf16 (hi/lo) for the MFMA
// out-projection. SPLIT_OUT=0: fp32 ctx (fallback path).
// ---------------------------------------------------------------------------
template <int SPLIT_OUT>
__global__ __launch_bounds__(256) void attn_kernel(
    const float* __restrict__ qkv, float* __restrict__ ctx,
    unsigned short* __restrict__ ctx_h, unsigned short* __restrict__ ctx_l)
{
    constexpr int LP = 68;

    const int h  = blockIdx.y;
    const int b  = blockIdx.z;
    const int q0 = blockIdx.x * 64;

    const size_t head_off = (((size_t)b * H + h) * S) * HD;
    const float* __restrict__ Q = qkv + head_off;
    const float* __restrict__ K = qkv + (size_t)BS * D + head_off;
    const float* __restrict__ V = qkv + 2 * (size_t)BS * D + head_off;

    __shared__ float QsT[HD][LP];
    __shared__ float KsT[HD][LP];
    __shared__ float Vs[64][LP];
    __shared__ float Ps[64][LP];

    const int tid = threadIdx.x;
    const int tx  = tid & 15;
    const int ty  = tid >> 4;

    const int st_r   = tid >> 4;
    const int st_col = (tid & 15) * 4;

    float acc[4][4] = {};
    float m_reg[4], l_reg[4];
#pragma unroll
    for (int i = 0; i < 4; ++i) { m_reg[i] = -__builtin_inff(); l_reg[i] = 0.f; }

    constexpr float SCL = 0.125f * 1.44269504088896f;
#pragma unroll
    for (int c = 0; c < 4; ++c) {
        const int r = st_r + c * 16;
        float4 v = *(const float4*)&Q[(size_t)(q0 + r) * HD + st_col];
        QsT[st_col + 0][r] = v.x * SCL;
        QsT[st_col + 1][r] = v.y * SCL;
        QsT[st_col + 2][r] = v.z * SCL;
        QsT[st_col + 3][r] = v.w * SCL;
    }

    float4 pk[4], pv[4];
    auto load_kv = [&](int kv0) {
#pragma unroll
        for (int c = 0; c < 4; ++c) {
            const int r = st_r + c * 16;
            pk[c] = *(const float4*)&K[(size_t)(kv0 + r) * HD + st_col];
            pv[c] = *(const float4*)&V[(size_t)(kv0 + r) * HD + st_col];
        }
    };

    load_kv(0);

    for (int kv0 = 0; kv0 < S; kv0 += 64) {
        __syncthreads();
#pragma unroll
        for (int c = 0; c < 4; ++c) {
            const int r = st_r + c * 16;
            KsT[st_col + 0][r] = pk[c].x;
            KsT[st_col + 1][r] = pk[c].y;
            KsT[st_col + 2][r] = pk[c].z;
            KsT[st_col + 3][r] = pk[c].w;
            *(float4*)&Vs[r][st_col] = pv[c];
        }
        __syncthreads();

        if (kv0 + 64 < S) load_kv(kv0 + 64);

        float s[4][4] = {};
#pragma unroll 2
        for (int d = 0; d < HD; ++d) {
            float4 a4 = *(const float4*)&QsT[d][ty * 4];
            float4 b4 = *(const float4*)&KsT[d][tx * 4];
            float a[4]  = {a4.x, a4.y, a4.z, a4.w};
            float bb[4] = {b4.x, b4.y, b4.z, b4.w};
#pragma unroll
            for (int i = 0; i < 4; ++i)
#pragma unroll
                for (int j = 0; j < 4; ++j)
                    s[i][j] += a[i] * bb[j];
        }

#pragma unroll
        for (int i = 0; i < 4; ++i) {
            float mx = fmaxf(fmaxf(s[i][0], s[i][1]), fmaxf(s[i][2], s[i][3]));
            mx = fmaxf(mx, __shfl_xor(mx, 1));
            mx = fmaxf(mx, __shfl_xor(mx, 2));
            mx = fmaxf(mx, __shfl_xor(mx, 4));
            mx = fmaxf(mx, __shfl_xor(mx, 8));
            const float m_new = fmaxf(m_reg[i], mx);
            const float alpha = EXP2F(m_reg[i] - m_new);
            float rs = 0.f;
#pragma unroll
            for (int j = 0; j < 4; ++j) {
                s[i][j] = EXP2F(s[i][j] - m_new);
                rs += s[i][j];
            }
            rs += __shfl_xor(rs, 1);
            rs += __shfl_xor(rs, 2);
            rs += __shfl_xor(rs, 4);
            rs += __shfl_xor(rs, 8);
            l_reg[i] = l_reg[i] * alpha + rs;
            m_reg[i] = m_new;
#pragma unroll
            for (int j = 0; j < 4; ++j)
                acc[i][j] *= alpha;
        }

#pragma unroll
        for (int i = 0; i < 4; ++i) {
            float4 w4 = make_float4(s[i][0], s[i][1], s[i][2], s[i][3]);
            *(float4*)&Ps[ty * 4 + i][tx * 4] = w4;
        }
        __syncthreads();

#pragma unroll 2
        for (int kq = 0; kq < 16; ++kq) {
            float4 p4[4];
#pragma unroll
            for (int i = 0; i < 4; ++i)
                p4[i] = *(const float4*)&Ps[ty * 4 + i][kq * 4];
            float pr[4][4] = {
                {p4[0].x, p4[0].y, p4[0].z, p4[0].w},
                {p4[1].x, p4[1].y, p4[1].z, p4[1].w},
                {p4[2].x, p4[2].y, p4[2].z, p4[2].w},
                {p4[3].x, p4[3].y, p4[3].z, p4[3].w}};
#pragma unroll
            for (int e = 0; e < 4; ++e) {
                float4 v4 = *(const float4*)&Vs[kq * 4 + e][tx * 4];
                float vv[4] = {v4.x, v4.y, v4.z, v4.w};
#pragma unroll
                for (int i = 0; i < 4; ++i)
#pragma unroll
                    for (int j = 0; j < 4; ++j)
                        acc[i][j] += pr[i][e] * vv[j];
            }
        }
    }

#pragma unroll
    for (int i = 0; i < 4; ++i) {
        const int q     = q0 + ty * 4 + i;
        const float inv = 1.f / l_reg[i];
        float o0 = acc[i][0] * inv, o1 = acc[i][1] * inv;
        float o2 = acc[i][2] * inv, o3 = acc[i][3] * inv;
        const size_t off = ((size_t)b * S + q) * D + h * HD + tx * 4;
        if constexpr (SPLIT_OUT) {
            ushort4 h4, l4;
            split2(o0, h4.x, l4.x);
            split2(o1, h4.y, l4.y);
            split2(o2, h4.z, l4.z);
            split2(o3, h4.w, l4.w);
            *(ushort4*)&ctx_h[off] = h4;
            *(ushort4*)&ctx_l[off] = l4;
        } else {
            *(float4*)&ctx[off] = make_float4(o0, o1, o2, o3);
        }
    }
}

// ---------------------------------------------------------------------------
// Fallback fp32 GEMM (round-7 verified) — used only if ws_size < 96MB.
// ---------------------------------------------------------------------------
template <int OUT_MODE, int TN>
__global__ __launch_bounds__(256) void gemm_fp32(
    const float* __restrict__ A,
    const float* __restrict__ W0, const float* __restrict__ b0,
    const float* __restrict__ W1, const float* __restrict__ b1,
    const float* __restrict__ W2, const float* __restrict__ b2,
    float* __restrict__ out)
{
    constexpr int TM = 128;
    constexpr int KT = 16;
    constexpr int NH = TN / 64;

    const int z = (OUT_MODE == 0) ? blockIdx.z : 0;
    const float* __restrict__ W    = (z == 0) ? W0 : (z == 1) ? W1 : W2;
    const float* __restrict__ bias = (z == 0) ? b0 : (z == 1) ? b1 : b2;

    __shared__ float As[2][KT][TM];
    __shared__ float Bs[2][KT][TN];

    const int tid = threadIdx.x;
    const int tx  = tid & 15;
    const int ty  = tid >> 4;
    const int m0  = blockIdx.x * TM;
    const int n0  = blockIdx.y * TN;

    const int a_row = tid >> 1;
    const int a_k   = (tid & 1) * 8;
    const int b_row = (TN == 64) ? (tid >> 4) : (tid >> 5);
    const int b_col = (TN == 64) ? ((tid & 15) * 4) : ((tid & 31) * 4);

    float acc[8][4 * NH] = {};

    float4 pa0, pa1, pb0, pb1;
    auto load_tile = [&](int k0) {
        pa0 = *(const float4*)&A[(size_t)(m0 + a_row) * D + k0 + a_k];
        pa1 = *(const float4*)&A[(size_t)(m0 + a_row) * D + k0 + a_k + 4];
        pb0 = *(const float4*)&W[(size_t)(k0 + b_row) * D + n0 + b_col];
        if constexpr (NH == 2)
            pb1 = *(const float4*)&W[(size_t)(k0 + b_row + 8) * D + n0 + b_col];
    };
    auto store_tile = [&](int buf) {
        As[buf][a_k + 0][a_row] = pa0.x;
        As[buf][a_k + 1][a_row] = pa0.y;
        As[buf][a_k + 2][a_row] = pa0.z;
        As[buf][a_k + 3][a_row] = pa0.w;
        As[buf][a_k + 4][a_row] = pa1.x;
        As[buf][a_k + 5][a_row] = pa1.y;
        As[buf][a_k + 6][a_row] = pa1.z;
        As[buf][a_k + 7][a_row] = pa1.w;
        *(float4*)&Bs[buf][b_row][b_col] = pb0;
        if constexpr (NH == 2)
            *(float4*)&Bs[buf][b_row + 8][b_col] = pb1;
    };

    load_tile(0);
    store_tile(0);
    int cur = 0;

    for (int k0 = 0; k0 < D; k0 += KT) {
        __syncthreads();
        const bool more = (k0 + KT < D);
        if (more) load_tile(k0 + KT);

        const float (*__restrict__ Asc)[TM] = As[cur];
        const float (*__restrict__ Bsc)[TN] = Bs[cur];
#pragma unroll
        for (int k = 0; k < KT; ++k) {
            float4 a0 = *(const float4*)&Asc[k][ty * 4];
            float4 a1 = *(const float4*)&Asc[k][64 + ty * 4];
            float4 c0 = *(const float4*)&Bsc[k][tx * 4];
            float a[8] = {a0.x, a0.y, a0.z, a0.w, a1.x, a1.y, a1.z, a1.w};
            float bb[4 * NH];
            bb[0] = c0.x; bb[1] = c0.y; bb[2] = c0.z; bb[3] = c0.w;
            if constexpr (NH == 2) {
                float4 c1 = *(const float4*)&Bsc[k][64 + tx * 4];
                bb[4] = c1.x; bb[5] = c1.y; bb[6] = c1.z; bb[7] = c1.w;
            }
#pragma unroll
            for (int i = 0; i < 8; ++i)
#pragma unroll
                for (int j = 0; j < 4 * NH; ++j)
                    acc[i][j] += a[i] * bb[j];
        }

        if (more) store_tile(cur ^ 1);
        cur ^= 1;
    }

#pragma unroll
    for (int mh = 0; mh < 2; ++mh) {
#pragma unroll
        for (int i = 0; i < 4; ++i) {
            const int m = m0 + mh * 64 + ty * 4 + i;
#pragma unroll
            for (int nh = 0; nh < NH; ++nh) {
                const int n = n0 + nh * 64 + tx * 4;
                float4 r;
                r.x = acc[mh * 4 + i][nh * 4 + 0] + bias[n + 0];
                r.y = acc[mh * 4 + i][nh * 4 + 1] + bias[n + 1];
                r.z = acc[mh * 4 + i][nh * 4 + 2] + bias[n + 2];
                r.w = acc[mh * 4 + i][nh * 4 + 3] + bias[n + 3];
                if constexpr (OUT_MODE == 1) {
                    *(float4*)&out[(size_t)m * D + n] = r;
                } else {
                    float* __restrict__ o = out + (size_t)z * BS * D;
                    const int bb2 = m >> 11;
                    const int s   = m & (S - 1);
                    const int h   = n >> 6;
                    const int d   = n & (HD - 1);
                    *(float4*)&o[(((size_t)bb2 * H + h) * S + s) * HD + d] = r;
                }
            }
        }
    }
}

// ---------------------------------------------------------------------------
extern "C" void kernel_launch(void* const* d_in, const int* in_sizes, int n_in,
                              void* d_out, int out_size, void* d_ws, size_t ws_size,
                              hipStream_t stream)
{
    const float* hs = (const float*)d_in[0];
    const float* Wq = (const float*)d_in[1];
    const float* bq = (const float*)d_in[2];
    const float* Wk = (const float*)d_in[3];
    const float* bk = (const float*)d_in[4];
    const float* Wv = (const float*)d_in[5];
    const float* bv = (const float*)d_in[6];
    const float* Wo = (const float*)d_in[7];
    const float* bo = (const float*)d_in[8];
    float* out = (float*)d_out;

    char* ws = (char*)d_ws;
    // workspace layout (bytes)
    const size_t qkv_b = (size_t)3 * BS * D * 4;     // 48MB fp32 qkv
    const size_t w_b   = (size_t)4 * D * D * 2;      // 8MB per split half
    const size_t a_b   = (size_t)BS * D * 2;         // 8MB per split half
    float*          qkv = (float*)ws;
    unsigned short* WTh = (unsigned short*)(ws + qkv_b);
    unsigned short* WTl = (unsigned short*)(ws + qkv_b + w_b);
    unsigned short* Ah  = (unsigned short*)(ws + qkv_b + 2 * w_b);
    unsigned short* Al  = (unsigned short*)(ws + qkv_b + 2 * w_b + a_b);
    unsigned short* Ch  = (unsigned short*)(ws + qkv_b + 2 * w_b + 2 * a_b);
    unsigned short* Cl  = (unsigned short*)(ws + qkv_b + 2 * w_b + 3 * a_b);
    const size_t need = qkv_b + 2 * w_b + 4 * a_b;   // 96MB

    dim3 blk(256);

    if (ws_size >= need) {
        // --- split-bf16 MFMA path ---
        wsplit_kernel<<<dim3(16, 16, 4), blk, 0, stream>>>(Wq, Wk, Wv, Wo, WTh, WTl);
        asplit_kernel<<<dim3(2048), blk, 0, stream>>>(hs, Ah, Al, BS * D / 4);
        mfma_gemm<0><<<dim3(BS / 128, D / 128, 3), blk, 0, stream>>>(
            Ah, Al, WTh, WTl, bq, bk, bv, qkv);
        attn_kernel<1><<<dim3(S / 64, H, B), blk, 0, stream>>>(qkv, nullptr, Ch, Cl);
        mfma_gemm<1><<<dim3(BS / 128, D / 128, 1), blk, 0, stream>>>(
            Ch, Cl, WTh, WTl, bo, bo, bo, out);
    } else {
        // --- fp32 fallback (round-7 verified), needs 64MB ---
        float* ctx = qkv + (size_t)3 * BS * D;
        gemm_fp32<0, 128><<<dim3(BS / 128, D / 128, 3), blk, 0, stream>>>(
            hs, Wq, bq, Wk, bk, Wv, bv, qkv);
        attn_kernel<0><<<dim3(S / 64, H, B), blk, 0, stream>>>(qkv, ctx, nullptr, nullptr);
        gemm_fp32<1, 64><<<dim3(BS / 128, D / 64, 1), blk, 0, stream>>>(
            ctx, Wo, bo, Wo, bo, Wo, bo, out);
    }
}

// Round 10
// 356.686 us; speedup vs baseline: 2.9428x; 2.2243x over previous
//
#include <hip/hip_runtime.h>

// glibc math.h (transitively included) declares __exp2f -> name collision.
#if __has_builtin(__builtin_amdgcn_exp2f)
#define EXP2F(x) __builtin_amdgcn_exp2f(x)
#else
#define EXP2F(x) exp2f(x)
#endif

typedef short bf16x8 __attribute__((ext_vector_type(8)));   // 8 bf16 = 4 VGPRs
typedef float f32x4  __attribute__((ext_vector_type(4)));

// Problem constants (match reference)
constexpr int B  = 2;
constexpr int S  = 2048;
constexpr int D  = 1024;
constexpr int H  = 16;
constexpr int HD = 64;
constexpr int BS = B * S;       // 4096 rows

// ---------------- bf16 split helpers (error ~2^-18 relative) ----------------
__device__ __forceinline__ unsigned short bf16_rne(float f) {
    unsigned int u = __builtin_bit_cast(unsigned int, f);
    u += 0x7FFFu + ((u >> 16) & 1u);
    return (unsigned short)(u >> 16);
}
__device__ __forceinline__ float bf16_f32(unsigned short h) {
    unsigned int u = (unsigned int)h << 16;
    return __builtin_bit_cast(float, u);
}
__device__ __forceinline__ void split2(float f, unsigned short& h, unsigned short& l) {
    h = bf16_rne(f);
    l = bf16_rne(f - bf16_f32(h));
}

// ---------------------------------------------------------------------------
// Prepass 1: transpose + split the 4 weight matrices.
// W[k][n] fp32 -> WT_h/WT_l [z][n][k] bf16  (z: 0=Wq 1=Wk 2=Wv 3=Wo)
// ---------------------------------------------------------------------------
__global__ __launch_bounds__(256) void wsplit_kernel(
    const float* __restrict__ W0, const float* __restrict__ W1,
    const float* __restrict__ W2, const float* __restrict__ W3,
    unsigned short* __restrict__ wt_h, unsigned short* __restrict__ wt_l)
{
    const int z = blockIdx.z;
    const float* __restrict__ W = (z == 0) ? W0 : (z == 1) ? W1 : (z == 2) ? W2 : W3;
    __shared__ float T[64][68];
    const int k0 = blockIdx.x * 64, n0 = blockIdx.y * 64;
    const int t = threadIdx.x;
    const int r = t >> 4, c4 = (t & 15) * 4;
#pragma unroll
    for (int cc = 0; cc < 4; ++cc) {
        const int k = r + cc * 16;
        float4 v = *(const float4*)&W[(size_t)(k0 + k) * D + n0 + c4];
        T[k][c4 + 0] = v.x; T[k][c4 + 1] = v.y; T[k][c4 + 2] = v.z; T[k][c4 + 3] = v.w;
    }
    __syncthreads();
    const size_t base = (size_t)z * D * D;
#pragma unroll
    for (int cc = 0; cc < 4; ++cc) {
        const int n = r + cc * 16;
        ushort4 h4, l4;
        split2(T[c4 + 0][n], h4.x, l4.x);
        split2(T[c4 + 1][n], h4.y, l4.y);
        split2(T[c4 + 2][n], h4.z, l4.z);
        split2(T[c4 + 3][n], h4.w, l4.w);
        const size_t o = base + (size_t)(n0 + n) * D + k0 + c4;
        *(ushort4*)&wt_h[o] = h4;
        *(ushort4*)&wt_l[o] = l4;
    }
}

// ---------------------------------------------------------------------------
// Prepass 2: elementwise split fp32 -> bf16 hi/lo (for hidden_states).
// ---------------------------------------------------------------------------
__global__ __launch_bounds__(256) void asplit_kernel(
    const float* __restrict__ x, unsigned short* __restrict__ xh,
    unsigned short* __restrict__ xl, int n4)
{
    for (int i = blockIdx.x * 256 + threadIdx.x; i < n4; i += gridDim.x * 256) {
        float4 v = ((const float4*)x)[i];
        ushort4 h4, l4;
        split2(v.x, h4.x, l4.x);
        split2(v.y, h4.y, l4.y);
        split2(v.z, h4.z, l4.z);
        split2(v.w, h4.w, l4.w);
        ((ushort4*)xh)[i] = h4;
        ((ushort4*)xl)[i] = l4;
    }
}

// ---------------------------------------------------------------------------
// Split-bf16 MFMA GEMM (verified round 8): C = A@W + bias via Ah*Wh+Ah*Wl+Al*Wh.
// ---------------------------------------------------------------------------
template <int OUT_MODE>
__global__ __launch_bounds__(256, 2) void mfma_gemm(
    const unsigned short* __restrict__ Ah, const unsigned short* __restrict__ Al,
    const unsigned short* __restrict__ Wh, const unsigned short* __restrict__ Wl,
    const float* __restrict__ b0, const float* __restrict__ b1,
    const float* __restrict__ b2, float* __restrict__ out)
{
    constexpr int BM = 128, BK = 32, LP = 40;
    const int z = (OUT_MODE == 0) ? blockIdx.z : 3;
    const float* __restrict__ bias = (OUT_MODE == 1) ? b0 : (z == 0 ? b0 : z == 1 ? b1 : b2);
    const unsigned short* __restrict__ WTh = Wh + (size_t)z * D * D;
    const unsigned short* __restrict__ WTl = Wl + (size_t)z * D * D;

    __shared__ __align__(16) unsigned short sm[2][4][BM][LP];  // [buf][Ah,Al,Wh,Wl]

    const int tid  = threadIdx.x;
    const int lane = tid & 63, wid = tid >> 6;
    const int wm = wid >> 1, wn = wid & 1;
    const int lrow = lane & 15, lk8 = (lane >> 4) * 8;
    const int m0 = blockIdx.x * BM, n0 = blockIdx.y * BM;

    const int srow = tid >> 1;
    const int sk   = (tid & 1) * 16;

    bf16x8 rah0, rah1, ral0, ral1, rwh0, rwh1, rwl0, rwl1;
    auto load_tile = [&](int k0) {
        const size_t ao = (size_t)(m0 + srow) * D + k0 + sk;
        rah0 = *(const bf16x8*)&Ah[ao];  rah1 = *(const bf16x8*)&Ah[ao + 8];
        ral0 = *(const bf16x8*)&Al[ao];  ral1 = *(const bf16x8*)&Al[ao + 8];
        const size_t wo = (size_t)(n0 + srow) * D + k0 + sk;
        rwh0 = *(const bf16x8*)&WTh[wo]; rwh1 = *(const bf16x8*)&WTh[wo + 8];
        rwl0 = *(const bf16x8*)&WTl[wo]; rwl1 = *(const bf16x8*)&WTl[wo + 8];
    };
    auto store_tile = [&](int buf) {
        *(bf16x8*)&sm[buf][0][srow][sk]     = rah0;
        *(bf16x8*)&sm[buf][0][srow][sk + 8] = rah1;
        *(bf16x8*)&sm[buf][1][srow][sk]     = ral0;
        *(bf16x8*)&sm[buf][1][srow][sk + 8] = ral1;
        *(bf16x8*)&sm[buf][2][srow][sk]     = rwh0;
        *(bf16x8*)&sm[buf][2][srow][sk + 8] = rwh1;
        *(bf16x8*)&sm[buf][3][srow][sk]     = rwl0;
        *(bf16x8*)&sm[buf][3][srow][sk + 8] = rwl1;
    };

    f32x4 acc[4][4] = {};

    load_tile(0);
    store_tile(0);
    int cur = 0;

    for (int ks = 0; ks < D / BK; ++ks) {
        __syncthreads();
        const bool more = (ks + 1 < D / BK);
        if (more) load_tile((ks + 1) * BK);

        bf16x8 ah[4], al[4], bh[4], bl[4];
#pragma unroll
        for (int m = 0; m < 4; ++m) {
            const int r = wm * 64 + m * 16 + lrow;
            ah[m] = *(const bf16x8*)&sm[cur][0][r][lk8];
            al[m] = *(const bf16x8*)&sm[cur][1][r][lk8];
        }
#pragma unroll
        for (int n = 0; n < 4; ++n) {
            const int r = wn * 64 + n * 16 + lrow;
            bh[n] = *(const bf16x8*)&sm[cur][2][r][lk8];
            bl[n] = *(const bf16x8*)&sm[cur][3][r][lk8];
        }
#pragma unroll
        for (int m = 0; m < 4; ++m)
#pragma unroll
            for (int n = 0; n < 4; ++n) {
                acc[m][n] = __builtin_amdgcn_mfma_f32_16x16x32_bf16(ah[m], bh[n], acc[m][n], 0, 0, 0);
                acc[m][n] = __builtin_amdgcn_mfma_f32_16x16x32_bf16(ah[m], bl[n], acc[m][n], 0, 0, 0);
                acc[m][n] = __builtin_amdgcn_mfma_f32_16x16x32_bf16(al[m], bh[n], acc[m][n], 0, 0, 0);
            }

        if (more) store_tile(cur ^ 1);
        cur ^= 1;
    }

#pragma unroll
    for (int m = 0; m < 4; ++m) {
        const int gm = m0 + wm * 64 + m * 16 + (lane >> 4) * 4;
#pragma unroll
        for (int n = 0; n < 4; ++n) {
            const int gn = n0 + wn * 64 + n * 16 + lrow;
            const float bv = bias[gn];
#pragma unroll
            for (int r = 0; r < 4; ++r) {
                const float v = acc[m][n][r] + bv;
                const int row = gm + r;
                if constexpr (OUT_MODE == 1) {
                    out[(size_t)row * D + gn] = v;
                } else {
                    float* __restrict__ o = out + (size_t)z * BS * D;
                    const int bb = row >> 11, s = row & (S - 1);
                    const int hh = gn >> 6, d = gn & (HD - 1);
                    o[(((size_t)bb * H + hh) * S + s) * HD + d] = v;
                }
            }
        }
    }
}

// ---------------------------------------------------------------------------
// MFMA flash attention per (b,h). 256 thr = 4 waves; wave w owns q rows
// q0+16w..+15. KV tiles of 64. All operands bf16 via mfma_f32_16x16x32_bf16
// (frag layouts identical to the verified mfma_gemm).
//  QK^T: A=Q (regs, 2 frags), B=K (LDS row-major [kv][72]) — no transposes.
//  D-layout: lane holds S[4*(l>>4)+r][16n+(l&15)] -> softmax = in-lane max
//  over n + shfl_xor{1,2,4,8} in 16-lane groups (r-indexed m/l state).
//  PV: P staged per-wave in LDS [16][72] (A-frag); V staged TRANSPOSED
//  Vt[do][kv] (B-frag b128 reads), loaded column-wise from global (coalesced
//  256B per instr). ctx accumulates in same D-layout; epilogue splits to
//  bf16 hi/lo for the MFMA out-projection.
// ---------------------------------------------------------------------------
__global__ __launch_bounds__(256) void attn_mfma(
    const float* __restrict__ qkv,
    unsigned short* __restrict__ ctx_h, unsigned short* __restrict__ ctx_l)
{
    constexpr int LPK = 72;   // bf16 row stride (144B, 16B-aligned)
    constexpr float SCL = 0.125f * 1.44269504088896f;

    const int h = blockIdx.y, b = blockIdx.z;
    const int q0 = blockIdx.x * 64;
    const size_t head_off = (((size_t)b * H + h) * S) * HD;
    const float* __restrict__ Q = qkv + head_off;
    const float* __restrict__ K = qkv + (size_t)BS * D + head_off;
    const float* __restrict__ V = qkv + 2 * (size_t)BS * D + head_off;

    __shared__ __align__(16) unsigned short Ks[64][LPK];
    __shared__ __align__(16) unsigned short Vt[64][LPK];
    __shared__ __align__(16) unsigned short Pw[4][16][LPK];

    const int tid  = threadIdx.x;
    const int lane = tid & 63, w = tid >> 6;
    const int l15  = lane & 15, l4 = lane >> 4;

    const int st_r = tid >> 4, st_col = (tid & 15) * 4;   // K staging map

    // Q fragments (A-frag): lane holds Q[q0+16w+l15][8*l4 + 32*ks + j], scaled
    bf16x8 qf[2];
    {
        const float* qrow = &Q[(size_t)(q0 + 16 * w + l15) * HD + 8 * l4];
#pragma unroll
        for (int ks = 0; ks < 2; ++ks) {
            float4 v0 = *(const float4*)&qrow[32 * ks];
            float4 v1 = *(const float4*)&qrow[32 * ks + 4];
            bf16x8 f;
            f[0] = (short)bf16_rne(v0.x * SCL);
            f[1] = (short)bf16_rne(v0.y * SCL);
            f[2] = (short)bf16_rne(v0.z * SCL);
            f[3] = (short)bf16_rne(v0.w * SCL);
            f[4] = (short)bf16_rne(v1.x * SCL);
            f[5] = (short)bf16_rne(v1.y * SCL);
            f[6] = (short)bf16_rne(v1.z * SCL);
            f[7] = (short)bf16_rne(v1.w * SCL);
            qf[ks] = f;
        }
    }

    float4 pk[4];        // K prefetch (row-major float4s)
    float  pvv[4][4];    // V prefetch (column-wise scalars for transpose)
    auto load_kv = [&](int kv0) {
#pragma unroll
        for (int c = 0; c < 4; ++c)
            pk[c] = *(const float4*)&K[(size_t)(kv0 + st_r + 16 * c) * HD + st_col];
#pragma unroll
        for (int cc = 0; cc < 4; ++cc)
#pragma unroll
            for (int i = 0; i < 4; ++i)
                pvv[cc][i] = V[(size_t)(kv0 + 16 * w + 4 * cc + i) * HD + lane];
    };

    f32x4 cacc[4] = {};
    float m_reg[4], l_reg[4];
#pragma unroll
    for (int r = 0; r < 4; ++r) { m_reg[r] = -__builtin_inff(); l_reg[r] = 0.f; }

    load_kv(0);

    for (int kv0 = 0; kv0 < S; kv0 += 64) {
        __syncthreads();   // all waves done reading Ks/Vt of previous tile
#pragma unroll
        for (int c = 0; c < 4; ++c) {
            ushort4 u;
            u.x = bf16_rne(pk[c].x); u.y = bf16_rne(pk[c].y);
            u.z = bf16_rne(pk[c].z); u.w = bf16_rne(pk[c].w);
            *(ushort4*)&Ks[st_r + 16 * c][st_col] = u;
        }
#pragma unroll
        for (int cc = 0; cc < 4; ++cc) {
            ushort4 u;
            u.x = bf16_rne(pvv[cc][0]); u.y = bf16_rne(pvv[cc][1]);
            u.z = bf16_rne(pvv[cc][2]); u.w = bf16_rne(pvv[cc][3]);
            *(ushort4*)&Vt[lane][16 * w + 4 * cc] = u;   // Vt[do][kv]
        }
        __syncthreads();

        if (kv0 + 64 < S) load_kv(kv0 + 64);   // flies under compute

        // S = Q K^T : 4 n-tiles x 2 k-steps
        f32x4 sacc[4] = {};
#pragma unroll
        for (int n = 0; n < 4; ++n)
#pragma unroll
            for (int ks = 0; ks < 2; ++ks) {
                bf16x8 kf = *(const bf16x8*)&Ks[16 * n + l15][8 * l4 + 32 * ks];
                sacc[n] = __builtin_amdgcn_mfma_f32_16x16x32_bf16(qf[ks], kf, sacc[n], 0, 0, 0);
            }

        // online softmax (rows q' = 4*l4 + r), P -> per-wave LDS as bf16
#pragma unroll
        for (int r = 0; r < 4; ++r) {
            float mx = fmaxf(fmaxf(sacc[0][r], sacc[1][r]), fmaxf(sacc[2][r], sacc[3][r]));
            mx = fmaxf(mx, __shfl_xor(mx, 1));
            mx = fmaxf(mx, __shfl_xor(mx, 2));
            mx = fmaxf(mx, __shfl_xor(mx, 4));
            mx = fmaxf(mx, __shfl_xor(mx, 8));
            const float m_new = fmaxf(m_reg[r], mx);
            const float alpha = EXP2F(m_reg[r] - m_new);
            float p[4], rs = 0.f;
#pragma unroll
            for (int n = 0; n < 4; ++n) { p[n] = EXP2F(sacc[n][r] - m_new); rs += p[n]; }
            rs += __shfl_xor(rs, 1);
            rs += __shfl_xor(rs, 2);
            rs += __shfl_xor(rs, 4);
            rs += __shfl_xor(rs, 8);
            l_reg[r] = l_reg[r] * alpha + rs;
            m_reg[r] = m_new;
#pragma unroll
            for (int n = 0; n < 4; ++n) {
                cacc[n][r] *= alpha;
                Pw[w][4 * l4 + r][16 * n + l15] = bf16_rne(p[n]);
            }
        }

        // ctx += P @ V  (A = P from own wave's LDS, B = Vt)
#pragma unroll
        for (int ks = 0; ks < 2; ++ks) {
            bf16x8 pa = *(const bf16x8*)&Pw[w][l15][8 * l4 + 32 * ks];
#pragma unroll
            for (int n = 0; n < 4; ++n) {
                bf16x8 vf = *(const bf16x8*)&Vt[16 * n + l15][8 * l4 + 32 * ks];
                cacc[n] = __builtin_amdgcn_mfma_f32_16x16x32_bf16(pa, vf, cacc[n], 0, 0, 0);
            }
        }
    }

    // normalize, split to bf16 hi/lo, write ctx [BS][D] (col = h*64 + do)
#pragma unroll
    for (int r = 0; r < 4; ++r) {
        const float inv = 1.f / l_reg[r];
        const int q = q0 + 16 * w + 4 * l4 + r;
#pragma unroll
        for (int n = 0; n < 4; ++n) {
            const float v = cacc[n][r] * inv;
            unsigned short hh, ll;
            split2(v, hh, ll);
            const size_t off = ((size_t)b * S + q) * D + h * HD + 16 * n + l15;
            ctx_h[off] = hh;
            ctx_l[off] = ll;
        }
    }
}

// ---------------------------------------------------------------------------
// fp32 fallback attention (round-7 verified) — only if ws too small.
// ---------------------------------------------------------------------------
__global__ __launch_bounds__(256) void attn_kernel(
    const float* __restrict__ qkv, float* __restrict__ ctx)
{
    constexpr int LP = 68;

    const int h  = blockIdx.y;
    const int b  = blockIdx.z;
    const int q0 = blockIdx.x * 64;

    const size_t head_off = (((size_t)b * H + h) * S) * HD;
    const float* __restrict__ Q = qkv + head_off;
    const float* __restrict__ K = qkv + (size_t)BS * D + head_off;
    const float* __restrict__ V = qkv + 2 * (size_t)BS * D + head_off;

    __shared__ float QsT[HD][LP];
    __shared__ float KsT[HD][LP];
    __shared__ float Vs[64][LP];
    __shared__ float Ps[64][LP];

    const int tid = threadIdx.x;
    const int tx  = tid & 15;
    const int ty  = tid >> 4;

    const int st_r   = tid >> 4;
    const int st_col = (tid & 15) * 4;

    float acc[4][4] = {};
    float m_reg[4], l_reg[4];
#pragma unroll
    for (int i = 0; i < 4; ++i) { m_reg[i] = -__builtin_inff(); l_reg[i] = 0.f; }

    constexpr float SCL = 0.125f * 1.44269504088896f;
#pragma unroll
    for (int c = 0; c < 4; ++c) {
        const int r = st_r + c * 16;
        float4 v = *(const float4*)&Q[(size_t)(q0 + r) * HD + st_col];
        QsT[st_col + 0][r] = v.x * SCL;
        QsT[st_col + 1][r] = v.y * SCL;
        QsT[st_col + 2][r] = v.z * SCL;
        QsT[st_col + 3][r] = v.w * SCL;
    }

    float4 pk[4], pv[4];
    auto load_kv = [&](int kv0) {
#pragma unroll
        for (int c = 0; c < 4; ++c) {
            const int r = st_r + c * 16;
            pk[c] = *(const float4*)&K[(size_t)(kv0 + r) * HD + st_col];
            pv[c] = *(const float4*)&V[(size_t)(kv0 + r) * HD + st_col];
        }
    };

    load_kv(0);

    for (int kv0 = 0; kv0 < S; kv0 += 64) {
        __syncthreads();
#pragma unroll
        for (int c = 0; c < 4; ++c) {
            const int r = st_r + c * 16;
            KsT[st_col + 0][r] = pk[c].x;
            KsT[st_col + 1][r] = pk[c].y;
            KsT[st_col + 2][r] = pk[c].z;
            KsT[st_col + 3][r] = pk[c].w;
            *(float4*)&Vs[r][st_col] = pv[c];
        }
        __syncthreads();

        if (kv0 + 64 < S) load_kv(kv0 + 64);

        float s[4][4] = {};
#pragma unroll 2
        for (int d = 0; d < HD; ++d) {
            float4 a4 = *(const float4*)&QsT[d][ty * 4];
            float4 b4 = *(const float4*)&KsT[d][tx * 4];
            float a[4]  = {a4.x, a4.y, a4.z, a4.w};
            float bb[4] = {b4.x, b4.y, b4.z, b4.w};
#pragma unroll
            for (int i = 0; i < 4; ++i)
#pragma unroll
                for (int j = 0; j < 4; ++j)
                    s[i][j] += a[i] * bb[j];
        }

#pragma unroll
        for (int i = 0; i < 4; ++i) {
            float mx = fmaxf(fmaxf(s[i][0], s[i][1]), fmaxf(s[i][2], s[i][3]));
            mx = fmaxf(mx, __shfl_xor(mx, 1));
            mx = fmaxf(mx, __shfl_xor(mx, 2));
            mx = fmaxf(mx, __shfl_xor(mx, 4));
            mx = fmaxf(mx, __shfl_xor(mx, 8));
            const float m_new = fmaxf(m_reg[i], mx);
            const float alpha = EXP2F(m_reg[i] - m_new);
            float rs = 0.f;
#pragma unroll
            for (int j = 0; j < 4; ++j) {
                s[i][j] = EXP2F(s[i][j] - m_new);
                rs += s[i][j];
            }
            rs += __shfl_xor(rs, 1);
            rs += __shfl_xor(rs, 2);
            rs += __shfl_xor(rs, 4);
            rs += __shfl_xor(rs, 8);
            l_reg[i] = l_reg[i] * alpha + rs;
            m_reg[i] = m_new;
#pragma unroll
            for (int j = 0; j < 4; ++j)
                acc[i][j] *= alpha;
        }

#pragma unroll
        for (int i = 0; i < 4; ++i) {
            float4 w4 = make_float4(s[i][0], s[i][1], s[i][2], s[i][3]);
            *(float4*)&Ps[ty * 4 + i][tx * 4] = w4;
        }
        __syncthreads();

#pragma unroll 2
        for (int kq = 0; kq < 16; ++kq) {
            float4 p4[4];
#pragma unroll
            for (int i = 0; i < 4; ++i)
                p4[i] = *(const float4*)&Ps[ty * 4 + i][kq * 4];
            float pr[4][4] = {
                {p4[0].x, p4[0].y, p4[0].z, p4[0].w},
                {p4[1].x, p4[1].y, p4[1].z, p4[1].w},
                {p4[2].x, p4[2].y, p4[2].z, p4[2].w},
                {p4[3].x, p4[3].y, p4[3].z, p4[3].w}};
#pragma unroll
            for (int e = 0; e < 4; ++e) {
                float4 v4 = *(const float4*)&Vs[kq * 4 + e][tx * 4];
                float vv[4] = {v4.x, v4.y, v4.z, v4.w};
#pragma unroll
                for (int i = 0; i < 4; ++i)
#pragma unroll
                    for (int j = 0; j < 4; ++j)
                        acc[i][j] += pr[i][e] * vv[j];
            }
        }
    }

#pragma unroll
    for (int i = 0; i < 4; ++i) {
        const int q     = q0 + ty * 4 + i;
        const float inv = 1.f / l_reg[i];
        float4 r;
        r.x = acc[i][0] * inv;
        r.y = acc[i][1] * inv;
        r.z = acc[i][2] * inv;
        r.w = acc[i][3] * inv;
        *(float4*)&ctx[((size_t)b * S + q) * D + h * HD + tx * 4] = r;
    }
}

// ---------------------------------------------------------------------------
// Fallback fp32 GEMM (round-7 verified) — used only if ws_size < 96MB.
// ---------------------------------------------------------------------------
template <int OUT_MODE, int TN>
__global__ __launch_bounds__(256) void gemm_fp32(
    const float* __restrict__ A,
    const float* __restrict__ W0, const float* __restrict__ b0,
    const float* __restrict__ W1, const float* __restrict__ b1,
    const float* __restrict__ W2, const float* __restrict__ b2,
    float* __restrict__ out)
{
    constexpr int TM = 128;
    constexpr int KT = 16;
    constexpr int NH = TN / 64;

    const int z = (OUT_MODE == 0) ? blockIdx.z : 0;
    const float* __restrict__ W    = (z == 0) ? W0 : (z == 1) ? W1 : W2;
    const float* __restrict__ bias = (z == 0) ? b0 : (z == 1) ? b1 : b2;

    __shared__ float As[2][KT][TM];
    __shared__ float Bs[2][KT][TN];

    const int tid = threadIdx.x;
    const int tx  = tid & 15;
    const int ty  = tid >> 4;
    const int m0  = blockIdx.x * TM;
    const int n0  = blockIdx.y * TN;

    const int a_row = tid >> 1;
    const int a_k   = (tid & 1) * 8;
    const int b_row = (TN == 64) ? (tid >> 4) : (tid >> 5);
    const int b_col = (TN == 64) ? ((tid & 15) * 4) : ((tid & 31) * 4);

    float acc[8][4 * NH] = {};

    float4 pa0, pa1, pb0, pb1;
    auto load_tile = [&](int k0) {
        pa0 = *(const float4*)&A[(size_t)(m0 + a_row) * D + k0 + a_k];
        pa1 = *(const float4*)&A[(size_t)(m0 + a_row) * D + k0 + a_k + 4];
        pb0 = *(const float4*)&W[(size_t)(k0 + b_row) * D + n0 + b_col];
        if constexpr (NH == 2)
            pb1 = *(const float4*)&W[(size_t)(k0 + b_row + 8) * D + n0 + b_col];
    };
    auto store_tile = [&](int buf) {
        As[buf][a_k + 0][a_row] = pa0.x;
        As[buf][a_k + 1][a_row] = pa0.y;
        As[buf][a_k + 2][a_row] = pa0.z;
        As[buf][a_k + 3][a_row] = pa0.w;
        As[buf][a_k + 4][a_row] = pa1.x;
        As[buf][a_k + 5][a_row] = pa1.y;
        As[buf][a_k + 6][a_row] = pa1.z;
        As[buf][a_k + 7][a_row] = pa1.w;
        *(float4*)&Bs[buf][b_row][b_col] = pb0;
        if constexpr (NH == 2)
            *(float4*)&Bs[buf][b_row + 8][b_col] = pb1;
    };

    load_tile(0);
    store_tile(0);
    int cur = 0;

    for (int k0 = 0; k0 < D; k0 += KT) {
        __syncthreads();
        const bool more = (k0 + KT < D);
        if (more) load_tile(k0 + KT);

        const float (*__restrict__ Asc)[TM] = As[cur];
        const float (*__restrict__ Bsc)[TN] = Bs[cur];
#pragma unroll
        for (int k = 0; k < KT; ++k) {
            float4 a0 = *(const float4*)&Asc[k][ty * 4];
            float4 a1 = *(const float4*)&Asc[k][64 + ty * 4];
            float4 c0 = *(const float4*)&Bsc[k][tx * 4];
            float a[8] = {a0.x, a0.y, a0.z, a0.w, a1.x, a1.y, a1.z, a1.w};
            float bb[4 * NH];
            bb[0] = c0.x; bb[1] = c0.y; bb[2] = c0.z; bb[3] = c0.w;
            if constexpr (NH == 2) {
                float4 c1 = *(const float4*)&Bsc[k][64 + tx * 4];
                bb[4] = c1.x; bb[5] = c1.y; bb[6] = c1.z; bb[7] = c1.w;
            }
#pragma unroll
            for (int i = 0; i < 8; ++i)
#pragma unroll
                for (int j = 0; j < 4 * NH; ++j)
                    acc[i][j] += a[i] * bb[j];
        }

        if (more) store_tile(cur ^ 1);
        cur ^= 1;
    }

#pragma unroll
    for (int mh = 0; mh < 2; ++mh) {
#pragma unroll
        for (int i = 0; i < 4; ++i) {
            const int m = m0 + mh * 64 + ty * 4 + i;
#pragma unroll
            for (int nh = 0; nh < NH; ++nh) {
                const int n = n0 + nh * 64 + tx * 4;
                float4 r;
                r.x = acc[mh * 4 + i][nh * 4 + 0] + bias[n + 0];
                r.y = acc[mh * 4 + i][nh * 4 + 1] + bias[n + 1];
                r.z = acc[mh * 4 + i][nh * 4 + 2] + bias[n + 2];
                r.w = acc[mh * 4 + i][nh * 4 + 3] + bias[n + 3];
                if constexpr (OUT_MODE == 1) {
                    *(float4*)&out[(size_t)m * D + n] = r;
                } else {
                    float* __restrict__ o = out + (size_t)z * BS * D;
                    const int bb2 = m >> 11;
                    const int s   = m & (S - 1);
                    const int h   = n >> 6;
                    const int d   = n & (HD - 1);
                    *(float4*)&o[(((size_t)bb2 * H + h) * S + s) * HD + d] = r;
                }
            }
        }
    }
}

// ---------------------------------------------------------------------------
extern "C" void kernel_launch(void* const* d_in, const int* in_sizes, int n_in,
                              void* d_out, int out_size, void* d_ws, size_t ws_size,
                              hipStream_t stream)
{
    const float* hs = (const float*)d_in[0];
    const float* Wq = (const float*)d_in[1];
    const float* bq = (const float*)d_in[2];
    const float* Wk = (const float*)d_in[3];
    const float* bk = (const float*)d_in[4];
    const float* Wv = (const float*)d_in[5];
    const float* bv = (const float*)d_in[6];
    const float* Wo = (const float*)d_in[7];
    const float* bo = (const float*)d_in[8];
    float* out = (float*)d_out;

    char* ws = (char*)d_ws;
    const size_t qkv_b = (size_t)3 * BS * D * 4;     // 48MB fp32 qkv
    const size_t w_b   = (size_t)4 * D * D * 2;      // 8MB per split half
    const size_t a_b   = (size_t)BS * D * 2;         // 8MB per split half
    float*          qkv = (float*)ws;
    unsigned short* WTh = (unsigned short*)(ws + qkv_b);
    unsigned short* WTl = (unsigned short*)(ws + qkv_b + w_b);
    unsigned short* Ah  = (unsigned short*)(ws + qkv_b + 2 * w_b);
    unsigned short* Al  = (unsigned short*)(ws + qkv_b + 2 * w_b + a_b);
    unsigned short* Ch  = (unsigned short*)(ws + qkv_b + 2 * w_b + 2 * a_b);
    unsigned short* Cl  = (unsigned short*)(ws + qkv_b + 2 * w_b + 3 * a_b);
    const size_t need = qkv_b + 2 * w_b + 4 * a_b;   // 96MB

    dim3 blk(256);

    if (ws_size >= need) {
        // --- full MFMA path ---
        wsplit_kernel<<<dim3(16, 16, 4), blk, 0, stream>>>(Wq, Wk, Wv, Wo, WTh, WTl);
        asplit_kernel<<<dim3(2048), blk, 0, stream>>>(hs, Ah, Al, BS * D / 4);
        mfma_gemm<0><<<dim3(BS / 128, D / 128, 3), blk, 0, stream>>>(
            Ah, Al, WTh, WTl, bq, bk, bv, qkv);
        attn_mfma<<<dim3(S / 64, H, B), blk, 0, stream>>>(qkv, Ch, Cl);
        mfma_gemm<1><<<dim3(BS / 128, D / 128, 1), blk, 0, stream>>>(
            Ch, Cl, WTh, WTl, bo, bo, bo, out);
    } else {
        // --- fp32 fallback (round-7 verified), needs 64MB ---
        float* ctx = qkv + (size_t)3 * BS * D;
        gemm_fp32<0, 128><<<dim3(BS / 128, D / 128, 3), blk, 0, stream>>>(
            hs, Wq, bq, Wk, bk, Wv, bv, qkv);
        attn_kernel<<<dim3(S / 64, H, B), blk, 0, stream>>>(qkv, ctx);
        gemm_fp32<1, 64><<<dim3(BS / 128, D / 64, 1), blk, 0, stream>>>(
            ctx, Wo, bo, Wo, bo, Wo, bo, out);
    }
}